// Round 12
// baseline (103.426 us; speedup 1.0000x reference)
//
#include <hip/hip_runtime.h>
#include <hip/hip_bf16.h>

typedef _Float16 f16;
typedef f16 f16x4 __attribute__((ext_vector_type(4)));
typedef f16 f16x8 __attribute__((ext_vector_type(8)));
typedef float f32x4 __attribute__((ext_vector_type(4)));

#define DIM   768
#define NP    196
#define BATCH 64
#define MROWS (BATCH * NP)        // 12544
#define NCOLS (3 * DIM)           // 2304
#define GRIDF 14.0f

// ---------------- Kernel 1: f32 -> f16 conversion of [Wq;Wk;Wv] + fused bias array ----------------
#define NW4   (DIM * DIM / 4)     // 147456 float4 per W
#define NB4   (NCOLS / 4)         // 576
#define NWCVT (3 * NW4 + NB4)

__global__ __launch_bounds__(256) void convert_w(
    const float* __restrict__ Wq, const float* __restrict__ Wk, const float* __restrict__ Wv,
    const float* __restrict__ bq, const float* __restrict__ bk, const float* __restrict__ bv,
    f16* __restrict__ W_h, float* __restrict__ bias_all) {
  int i = blockIdx.x * 256 + threadIdx.x;
  if (i >= NWCVT) return;
  if (i < 3 * NW4) {
    const float* src;
    f16* dst;
    int j = i;
    if (j < NW4)          { src = Wq; dst = W_h; }
    else if (j < 2 * NW4) { src = Wk; dst = W_h + DIM * DIM;     j -= NW4; }
    else                  { src = Wv; dst = W_h + 2 * DIM * DIM; j -= 2 * NW4; }
    float4 v = ((const float4*)src)[j];
    f16x4 h;
    h[0] = (f16)v.x; h[1] = (f16)v.y; h[2] = (f16)v.z; h[3] = (f16)v.w;
    ((f16x4*)dst)[j] = h;
  } else {
    int j = i - 3 * NW4;   // 0..575
    float4 v = (j < 192) ? ((const float4*)bq)[j]
             : (j < 384) ? ((const float4*)bk)[j - 192]
                         : ((const float4*)bv)[j - 384];
    ((float4*)bias_all)[j] = v;
  }
}

// ---------------- Kernel 2: qkv = x(f32!) @ W_h^T + bias -----------------------------------------
// x staged DIRECTLY as f32 via global_load_lds (no x_h buffer, no convert-x pass);
// f32->f16 conversion happens on the fragment-read path (2x ds_read_b128 + 8 v_cvt / frag).
// BM=BN=256, BK=32, 8 waves (2M x 4N), wave tile 128x64, acc[8][4]=128 VGPR.
// LDS 96KB: sA f32 2x32KB @ [0,64K) | sB f16 2x16KB @ [64K,96K). 441 blocks, 1 block/CU.
// Swizzles (derived, both 2-way residual = free per m136):
//   A (8 slots/row of 4 f32): slot = (2kg+j) ^ (row&7)
//   B (4 slots/row of 8 f16): slot = kg ^ ((row>>1)&3)
// Schedule per K-tile (r10 2-barrier): 4 B + 16 A ds_reads; cvt-lo; 16 MFMA(lo);
//   lgkm(0); BAR; stage kt+2 (6 gl_lds: A 4 + B 2); 16 MFMA(hi); vmcnt(6); BAR.
// vmcnt ledger: 6 issues/tile; at wait outstanding = {kt+1:6, kt+2:6} -> vmcnt(6) drains kt+1.
#define BM 256
#define BN 256
#define BK 32
#define NT (DIM / BK)   // 24

__device__ __forceinline__ void gl_lds16(const void* g, void* l) {
  __builtin_amdgcn_global_load_lds(
      (const __attribute__((address_space(1))) void*)g,
      (__attribute__((address_space(3))) void*)l, 16, 0, 0);
}

#define MFMA16(acc_, av, bv) acc_ = __builtin_amdgcn_mfma_f32_16x16x32_f16(av, bv, acc_, 0, 0, 0)
#define BAR    __builtin_amdgcn_s_barrier()
#define LGKM8  asm volatile("s_waitcnt lgkmcnt(8)" ::: "memory")
#define LGKM0  asm volatile("s_waitcnt lgkmcnt(0)" ::: "memory")
#define VMCNT6 asm volatile("s_waitcnt vmcnt(6)" ::: "memory")
#define VMCNT0 asm volatile("s_waitcnt vmcnt(0)" ::: "memory")

__global__ __launch_bounds__(512, 2) void gemm_qkv(
    const float* __restrict__ X, const f16* __restrict__ W,
    const float* __restrict__ bias_all, f16* __restrict__ C) {
  __shared__ __align__(16) char lds[98304];   // 96 KB

  const int t    = threadIdx.x;
  const int lane = t & 63;
  const int wid  = t >> 6;
  const int wr   = wid >> 2;       // 0..1 (M)
  const int wc   = wid & 3;        // 0..3 (N)

  // Bijective XCD swizzle (m204) over 441 blocks; n fastest (9 N-blocks)
  const int nwg = 49 * 9, qq = nwg / 8, rr = nwg % 8;   // q=55, r=1
  const int xcd = blockIdx.x & 7, seq = blockIdx.x >> 3;
  const int logical = (xcd < rr ? xcd * (qq + 1) : rr * (qq + 1) + (xcd - rr) * qq) + seq;
  const int bm0 = (logical / 9) * BM;
  const int bn0 = (logical % 9) * BN;

  // ---- Staging coords ----
  // A (f32): 256 rows x 32 f32 = 32KB = 2048 slots(16B); 512 thr -> 4 issues (chunks of 64 rows)
  const int srA = t >> 3;                       // 0..63
  const int ssA = t & 7;
  const int gcA = 4 * (ssA ^ (srA & 7));        // pre-swizzled f32 col
  const float* gA = X + (size_t)(bm0 + srA) * DIM + gcA;
  // B (f16): 256 rows x 32 f16 = 16KB = 1024 slots; 2 issues (chunks of 128 rows)
  const int srB = t >> 2;                       // 0..127
  const int ssB = t & 3;
  const int gcB = 8 * (ssB ^ ((srB >> 1) & 3)); // pre-swizzled f16 col
  const f16* gBp = W + (size_t)(bn0 + srB) * DIM + gcB;

#define STAGE(kt) do {                                                 \
    const int _b = (kt) & 1;                                           \
    const float* _ga = gA + (kt) * BK;                                 \
    char* _la = lds + _b * 32768 + t * 16;                             \
    gl_lds16(_ga,                     _la);                            \
    gl_lds16(_ga + (size_t) 64 * DIM, _la + 8192);                     \
    gl_lds16(_ga + (size_t)128 * DIM, _la + 16384);                    \
    gl_lds16(_ga + (size_t)192 * DIM, _la + 24576);                    \
    const f16* _gb = gBp + (kt) * BK;                                  \
    char* _lb = lds + 65536 + _b * 16384 + t * 16;                     \
    gl_lds16(_gb,                     _lb);                            \
    gl_lds16(_gb + (size_t)128 * DIM, _lb + 8192);                     \
  } while (0)

  // ---- Fragment-read coords ----
  const int rl = lane & 15;
  const int kg = lane >> 4;                     // 0..3
  const int sA0 = ((2 * kg)     ^ (rl & 7)) * 4;   // f32 units
  const int sA1 = ((2 * kg + 1) ^ (rl & 7)) * 4;
  const int sB8 = (kg ^ ((rl >> 1) & 3)) * 8;      // f16 units
  const int aBase = (wr * 128 + rl) * 32;          // f32 units (row stride 32 f32)
  const int bBase = (wc * 64 + rl) * 32;           // f16 units (row stride 32 f16)

  f32x4 acc[8][4] = {};
  f16x8 afrL[4], afrH[4], bfr[4];
  f32x4 rlo[4][2], rhi[4][2];

#define SAp(b_) ((const float*)(lds + (b_) * 32768))
#define SBp(b_) ((const f16*)(lds + 65536 + (b_) * 16384))

#define LDB(b_) do {                                                            \
    _Pragma("unroll") for (int ni = 0; ni < 4; ++ni)                            \
      bfr[ni] = *(const f16x8*)&SBp(b_)[bBase + ni * 512 + sB8];                \
    } while (0)

#define LDA_LO(b_) do {                                                         \
    _Pragma("unroll") for (int mi = 0; mi < 4; ++mi) {                          \
      rlo[mi][0] = *(const f32x4*)&SAp(b_)[aBase + mi * 512 + sA0];             \
      rlo[mi][1] = *(const f32x4*)&SAp(b_)[aBase + mi * 512 + sA1];             \
    } } while (0)

#define LDA_HI(b_) do {                                                         \
    _Pragma("unroll") for (int mi = 0; mi < 4; ++mi) {                          \
      rhi[mi][0] = *(const f32x4*)&SAp(b_)[aBase + (mi + 4) * 512 + sA0];       \
      rhi[mi][1] = *(const f32x4*)&SAp(b_)[aBase + (mi + 4) * 512 + sA1];       \
    } } while (0)

#define CVT8v(dst_, lo_, hi_) do {                                              \
    dst_[0]=(f16)lo_[0]; dst_[1]=(f16)lo_[1]; dst_[2]=(f16)lo_[2]; dst_[3]=(f16)lo_[3]; \
    dst_[4]=(f16)hi_[0]; dst_[5]=(f16)hi_[1]; dst_[6]=(f16)hi_[2]; dst_[7]=(f16)hi_[3]; } while (0)

#define CVT_LO do { _Pragma("unroll") for (int mi = 0; mi < 4; ++mi) CVT8v(afrL[mi], rlo[mi][0], rlo[mi][1]); } while (0)
#define CVT_HI do { _Pragma("unroll") for (int mi = 0; mi < 4; ++mi) CVT8v(afrH[mi], rhi[mi][0], rhi[mi][1]); } while (0)

  // SWAPPED operand order: mfma(bfr, afr) -> m = lane&15 (A row), n = 4*kg + reg (B row)
#define MMA_LO do {                                                              \
    __builtin_amdgcn_s_setprio(1);                                               \
    _Pragma("unroll") for (int ni = 0; ni < 4; ++ni)                             \
      _Pragma("unroll") for (int mi = 0; mi < 4; ++mi)                           \
        MFMA16(acc[mi][ni], bfr[ni], afrL[mi]);                                  \
    __builtin_amdgcn_s_setprio(0); } while (0)

#define MMA_HI do {                                                              \
    __builtin_amdgcn_s_setprio(1);                                               \
    _Pragma("unroll") for (int ni = 0; ni < 4; ++ni)                             \
      _Pragma("unroll") for (int mi = 0; mi < 4; ++mi)                           \
        MFMA16(acc[mi + 4][ni], bfr[ni], afrH[mi]);                              \
    __builtin_amdgcn_s_setprio(0); } while (0)

  // ---- Prologue: stage tiles 0,1 (6 issues each); drain tile0, tile1 stays in flight
  STAGE(0);
  STAGE(1);
  VMCNT6;
  BAR;

  for (int kt = 0; kt < NT; ++kt) {
    const int b = kt & 1;
    const bool more = (kt + 2 < NT);
    LDB(b); LDA_LO(b); LDA_HI(b);   // 4 + 8 + 8 ds_reads, in this order
    LGKM8;                           // B + A-lo resident; A-hi drains under cvt+MMA
    CVT_LO;
    MMA_LO;
    LGKM0;                           // A-hi resident; all reads of buf b complete
    CVT_HI;
    BAR;                             // -> buf b reusable by staging
    if (more) STAGE(kt + 2);
    MMA_HI;
    if (more) { VMCNT6; } else { VMCNT0; }   // tile kt+1 landed
    BAR;
  }

  // ---- Epilogue: 2 half-tile passes through 64KB LDS (bias fused) -> coalesced 16B stores
  // m = bm0 + wr*128 + mi*16 + rl ; n = bn0 + wc*64 + ni*16 + 4*kg + v
  {
    f16* eL = (f16*)lds;             // 128 rows x 256 f16 = 64KB
    const int nq0  = wc * 64 + 4 * kg;
    const int rrow = t >> 5;         // 0..15
    const int rchk = t & 31;         // 0..31 (8 f16 each)
#pragma unroll
    for (int p = 0; p < 2; ++p) {
      if (wr == p) {
#pragma unroll
        for (int ni = 0; ni < 4; ++ni) {
          const int nloc = nq0 + ni * 16;
          const float4 b4 = *(const float4*)&bias_all[bn0 + nloc];
#pragma unroll
          for (int mi = 0; mi < 8; ++mi) {
            const int e = mi * 16 + rl;     // 0..127
            f16x4 h;
            h[0] = (f16)(acc[mi][ni][0] + b4.x);
            h[1] = (f16)(acc[mi][ni][1] + b4.y);
            h[2] = (f16)(acc[mi][ni][2] + b4.z);
            h[3] = (f16)(acc[mi][ni][3] + b4.w);
            *(f16x4*)&eL[e * 256 + (nloc ^ ((e & 7) << 3))] = h;
          }
        }
      }
      LGKM0; BAR;
#pragma unroll
      for (int it = 0; it < 8; ++it) {
        const int row = it * 16 + rrow;
        f16x8 vdat = *(const f16x8*)&eL[row * 256 + ((rchk * 8) ^ ((row & 7) << 3))];
        *(f16x8*)&C[(size_t)(bm0 + p * 128 + row) * NCOLS + bn0 + rchk * 8] = vdat;
      }
      LGKM0; BAR;
    }
  }
}

// ---------------- Kernel 3: gather + 4-way per-feature softmax + weighted sum ----------------
// XCD-chunked block swizzle: 3136 blocks = 8 * 392; each XCD gets 392 consecutive blocks.
__global__ __launch_bounds__(256) void attend(
    const f16* __restrict__ qkv,
    const int* __restrict__ img_ids, const float* __restrict__ eps,
    const float* __restrict__ avgs, const float* __restrict__ stds,
    float* __restrict__ out) {
  const int lane = threadIdx.x & 63;
  const int wid  = threadIdx.x >> 6;
  const int logical = (blockIdx.x & 7) * 392 + (blockIdx.x >> 3);
  const int gw = logical * 4 + wid;          // (b*196 + s)
  const int b = gw / NP;
  const int s = gw - b * NP;

  const int img = img_ids[b];
  const float ex = eps[(b * 2 + 0) * NP + s];
  const float ey = eps[(b * 2 + 1) * NP + s];
  const float mux = avgs[(img * 2 + 0) * NP + s];
  const float muy = avgs[(img * 2 + 1) * NP + s];
  const float sdx = stds[(img * 2 + 0) * NP + s];
  const float sdy = stds[(img * 2 + 1) * NP + s];

  const float kx = fmaf(sdx, ex, mux);
  const float ky = fmaf(sdy, ey, muy);
  const float kx1 = ceilf(kx), kx2 = floorf(kx);
  const float ky1 = ceilf(ky), ky2 = floorf(ky);

  int idx[4];
  idx[0] = (int)fminf(fmaxf(GRIDF * ky1 + kx1, 0.0f), 195.0f);
  idx[1] = (int)fminf(fmaxf(GRIDF * ky1 + kx2, 0.0f), 195.0f);
  idx[2] = (int)fminf(fmaxf(GRIDF * ky2 + kx1, 0.0f), 195.0f);
  idx[3] = (int)fminf(fmaxf(GRIDF * ky2 + kx2, 0.0f), 195.0f);

  const f16* qrow = qkv + (size_t)gw * NCOLS;
  const f16* base = qkv + (size_t)(b * NP) * NCOLS;
  const f16* k0p = base + (size_t)idx[0] * NCOLS + DIM;
  const f16* k1p = base + (size_t)idx[1] * NCOLS + DIM;
  const f16* k2p = base + (size_t)idx[2] * NCOLS + DIM;
  const f16* k3p = base + (size_t)idx[3] * NCOLS + DIM;
  const f16* v0p = k0p + DIM;
  const f16* v1p = k1p + DIM;
  const f16* v2p = k2p + DIM;
  const f16* v3p = k3p + DIM;
  float* orow = out + (size_t)gw * DIM;

#pragma unroll
  for (int seg = 0; seg < 3; ++seg) {
    const int e0 = seg * 256 + lane * 4;
    f16x4 qv  = *(const f16x4*)(qrow + e0);
    f16x4 kv0 = *(const f16x4*)(k0p + e0);
    f16x4 kv1 = *(const f16x4*)(k1p + e0);
    f16x4 kv2 = *(const f16x4*)(k2p + e0);
    f16x4 kv3 = *(const f16x4*)(k3p + e0);
    f16x4 vv0 = *(const f16x4*)(v0p + e0);
    f16x4 vv1 = *(const f16x4*)(v1p + e0);
    f16x4 vv2 = *(const f16x4*)(v2p + e0);
    f16x4 vv3 = *(const f16x4*)(v3p + e0);
    float4 o;
    float* op = &o.x;
#pragma unroll
    for (int c = 0; c < 4; ++c) {
      const float q = (float)qv[c];
      const float s0 = q * (float)kv0[c];
      const float s1 = q * (float)kv1[c];
      const float s2 = q * (float)kv2[c];
      const float s3 = q * (float)kv3[c];
      const float mx = fmaxf(fmaxf(s0, s1), fmaxf(s2, s3));
      const float w0 = __expf(s0 - mx);
      const float w1 = __expf(s1 - mx);
      const float w2 = __expf(s2 - mx);
      const float w3 = __expf(s3 - mx);
      const float den = w0 + w1 + w2 + w3;
      const float num = w0 * (float)vv0[c] + w1 * (float)vv1[c] +
                        w2 * (float)vv2[c] + w3 * (float)vv3[c];
      op[c] = num / den;
    }
    *(float4*)(orow + e0) = o;
  }
}

// ---------------- Launch ----------------
extern "C" void kernel_launch(void* const* d_in, const int* in_sizes, int n_in,
                              void* d_out, int out_size, void* d_ws, size_t ws_size,
                              hipStream_t stream) {
  const float* x       = (const float*)d_in[0];
  const int*   img_ids = (const int*)d_in[2];
  const float* eps     = (const float*)d_in[3];
  const float* Wq      = (const float*)d_in[4];
  const float* bq      = (const float*)d_in[5];
  const float* Wk      = (const float*)d_in[6];
  const float* bk      = (const float*)d_in[7];
  const float* Wv      = (const float*)d_in[8];
  const float* bv      = (const float*)d_in[9];
  const float* avgs    = (const float*)d_in[10];
  const float* stds    = (const float*)d_in[11];
  float* out = (float*)d_out;

  char* ws = (char*)d_ws;
  const size_t WH_BYTES = (size_t)NCOLS * DIM * 2;   // 3,538,944
  const size_t BI_BYTES = (size_t)NCOLS * 4;         //     9,216
  f16*   W_h      = (f16*)ws;
  float* bias_all = (float*)(ws + WH_BYTES);
  f16*   qkv      = (f16*)(ws + WH_BYTES + BI_BYTES);

  {
    int grid = (NWCVT + 255) / 256;
    convert_w<<<grid, 256, 0, stream>>>(Wq, Wk, Wv, bq, bk, bv, W_h, bias_all);
  }
  {
    gemm_qkv<<<441, 512, 0, stream>>>(x, W_h, bias_all, qkv);
  }
  {
    int grid = MROWS / 4;
    attend<<<grid, 256, 0, stream>>>(qkv, img_ids, eps, avgs, stds, out);
  }
}

// Round 13
// 84.006 us; speedup vs baseline: 1.2312x; 1.2312x over previous
//
#include <hip/hip_runtime.h>
#include <hip/hip_bf16.h>

typedef _Float16 f16;
typedef f16 f16x4 __attribute__((ext_vector_type(4)));
typedef f16 f16x8 __attribute__((ext_vector_type(8)));
typedef float f32x4 __attribute__((ext_vector_type(4)));

#define DIM   768
#define NP    196
#define BATCH 64
#define MROWS (BATCH * NP)        // 12544
#define NCOLS (3 * DIM)           // 2304
#define GRIDF 14.0f

// ---------------- Kernel 1: f32 -> f16 conversion of x and [Wq;Wk;Wv] + bias array ----------------
#define NX4   (MROWS * DIM / 4)   // 2,408,448
#define NW4   (DIM * DIM / 4)     // 147,456 per W
#define NB4   (NCOLS / 4)         // 576
#define NCVTA (NX4 + 3 * NW4 + NB4)

__global__ __launch_bounds__(256) void convert_inputs(
    const float* __restrict__ x,
    const float* __restrict__ Wq, const float* __restrict__ Wk, const float* __restrict__ Wv,
    const float* __restrict__ bq, const float* __restrict__ bk, const float* __restrict__ bv,
    f16* __restrict__ x_h, f16* __restrict__ W_h, float* __restrict__ bias_all) {
  int i = blockIdx.x * 256 + threadIdx.x;
  if (i >= NCVTA) return;
  if (i < NX4 + 3 * NW4) {
    const float* src;
    f16* dst;
    int j;
    if (i < NX4) { src = x; dst = x_h; j = i; }
    else {
      j = i - NX4;
      if (j < NW4)          { src = Wq; dst = W_h; }
      else if (j < 2 * NW4) { src = Wk; dst = W_h + DIM * DIM;     j -= NW4; }
      else                  { src = Wv; dst = W_h + 2 * DIM * DIM; j -= 2 * NW4; }
    }
    float4 v = ((const float4*)src)[j];
    f16x4 h;
    h[0] = (f16)v.x; h[1] = (f16)v.y; h[2] = (f16)v.z; h[3] = (f16)v.w;
    ((f16x4*)dst)[j] = h;
  } else {
    int j = i - (NX4 + 3 * NW4);   // 0..575
    float4 v = (j < 192) ? ((const float4*)bq)[j]
             : (j < 384) ? ((const float4*)bk)[j - 192]
                         : ((const float4*)bv)[j - 384];
    ((float4*)bias_all)[j] = v;
  }
}

// ---------------- Kernel 2: qkv = x_h @ W_h^T + bias (256x256 8-phase, r3 main loop) ----------------
// A: (12544 x 768) f16 rm. W: (2304 x 768) f16 rm (B^T). BM=BN=256, BK=64,
// 8 waves (2M x 4N), wave tile 128x64. Both operands via global_load_lds (m151:
// gload_lds beats reg-staging at linear-LDS tiles). XOR-slot swizzle via
// pre-swizzled global source + swizzled ds_read. Counted vmcnt(4) at ph4/ph8.
// Epilogue: swapped-operand acc -> swizzled LDS C-tile -> coalesced 16B stores.

#define BM 256
#define BN 256
#define BK 64
#define NT    (DIM / BK)   // 12
#define NITER (NT / 2)     // 6

__device__ __forceinline__ void gl_lds16(const f16* g, f16* l) {
  __builtin_amdgcn_global_load_lds(
      (const __attribute__((address_space(1))) void*)g,
      (__attribute__((address_space(3))) void*)l, 16, 0, 0);
}

#define MFMA16(acc_, av, bv) acc_ = __builtin_amdgcn_mfma_f32_16x16x32_f16(av, bv, acc_, 0, 0, 0)
#define BAR    __builtin_amdgcn_s_barrier()
#define LGKM0  asm volatile("s_waitcnt lgkmcnt(0)" ::: "memory")
#define VMCNT4 asm volatile("s_waitcnt vmcnt(4)" ::: "memory")
#define VMCNT0 asm volatile("s_waitcnt vmcnt(0)" ::: "memory")

#define sAoff(buf) ((buf) * (BM * BK))
#define sBoff(buf) (2 * BM * BK + (buf) * (BN * BK))

__global__ __launch_bounds__(512, 2) void gemm_qkv(
    const f16* __restrict__ A, const f16* __restrict__ W,
    const float* __restrict__ bias_all, f16* __restrict__ C) {
  __shared__ __align__(16) f16 lds[2 * BM * BK + 2 * BN * BK];  // 131072 B

  const int t    = threadIdx.x;
  const int lane = t & 63;
  const int wid  = t >> 6;
  const int wr   = wid >> 2;       // 0..1  (M)
  const int wc   = wid & 3;        // 0..3  (N)

  // Bijective XCD swizzle (m204) over 441 blocks; logical: n fastest (9 N-blocks)
  const int nwg = 49 * 9, qq = nwg / 8, rr = nwg % 8;
  const int xcd = blockIdx.x & 7, seq = blockIdx.x >> 3;
  const int logical = (xcd < rr ? xcd * (qq + 1) : rr * (qq + 1) + (xcd - rr) * qq) + seq;
  const int bm0 = (logical / 9) * BM;
  const int bn0 = (logical % 9) * BN;

  // Staging coords: thread covers (row = t>>3, slot = t&7); source col pre-swizzled, LDS linear.
  const int srow  = t >> 3;                    // 0..63
  const int sslot = t & 7;
  const int gcol  = 8 * (sslot ^ (srow & 7));  // swizzled source column (elements)
  const int lds_off = srow * BK + sslot * 8;   // linear dest (f16)
  const f16* gAr = A + (size_t)(bm0 + srow) * DIM + gcol;
  const f16* gBr = W + (size_t)(bn0 + srow) * DIM + gcol;

#define STAGE_A(kt, h) do {                                          \
    const f16* _g = gAr + (size_t)((h) * 128) * DIM + (kt) * BK;     \
    f16* _l = &lds[sAoff((kt) & 1) + (h) * 128 * BK + lds_off];      \
    gl_lds16(_g, _l);                                                \
    gl_lds16(_g + (size_t)64 * DIM, _l + 64 * BK);                   \
  } while (0)

#define STAGE_B(kt, h) do {                                          \
    const f16* _g = gBr + (size_t)((h) * 128) * DIM + (kt) * BK;     \
    f16* _l = &lds[sBoff((kt) & 1) + (h) * 128 * BK + lds_off];      \
    gl_lds16(_g, _l);                                                \
    gl_lds16(_g + (size_t)64 * DIM, _l + 64 * BK);                   \
  } while (0)

  // Fragment-read coords
  const int rl = lane & 15;
  const int kg = lane >> 4;        // 0..3
  const int s7 = lane & 7;
  const int slot0 = ((0 * 4 + kg) ^ s7) * 8;   // kh=0 swizzled slot (f16)
  const int slot1 = ((1 * 4 + kg) ^ s7) * 8;   // kh=1
  const int aBase = (wr * 128 + rl) * BK;
  const int bBase = (wc * 64 + rl) * BK;

  f32x4 acc[8][4] = {};
  f16x8 afr[2][2], bfr[4][2];

#define LDB(buf) do {                                                                   \
    _Pragma("unroll") for (int ni = 0; ni < 4; ++ni) {                                  \
      bfr[ni][0] = *(const f16x8*)&lds[sBoff(buf) + bBase + ni * 16 * BK + slot0];      \
      bfr[ni][1] = *(const f16x8*)&lds[sBoff(buf) + bBase + ni * 16 * BK + slot1];      \
    } } while (0)

#define LDA(buf, q_) do {                                                               \
    _Pragma("unroll") for (int mm = 0; mm < 2; ++mm) {                                  \
      afr[mm][0] = *(const f16x8*)&lds[sAoff(buf) + aBase + ((q_) * 2 + mm) * 16 * BK + slot0]; \
      afr[mm][1] = *(const f16x8*)&lds[sAoff(buf) + aBase + ((q_) * 2 + mm) * 16 * BK + slot1]; \
    } } while (0)

  // SWAPPED operand order: mfma(bfr, afr) -> m = lane&15, n = 4*(lane>>4)+reg (contiguous cols/lane)
#define MMA(q_) do {                                                                    \
    __builtin_amdgcn_s_setprio(1);                                                      \
    _Pragma("unroll") for (int ni = 0; ni < 4; ++ni) {                                  \
      MFMA16(acc[(q_) * 2 + 0][ni], bfr[ni][0], afr[0][0]);                             \
      MFMA16(acc[(q_) * 2 + 1][ni], bfr[ni][0], afr[1][0]);                             \
      MFMA16(acc[(q_) * 2 + 0][ni], bfr[ni][1], afr[0][1]);                             \
      MFMA16(acc[(q_) * 2 + 1][ni], bfr[ni][1], afr[1][1]);                             \
    }                                                                                   \
    __builtin_amdgcn_s_setprio(0); } while (0)

  // ---- Prologue: tile0 full + tile1 B; tile0 landed via vmcnt(4), tile1.B in flight
  STAGE_A(0, 0); STAGE_A(0, 1); STAGE_B(0, 0); STAGE_B(0, 1);
  STAGE_B(1, 0); STAGE_B(1, 1);
  VMCNT4;
  BAR;

  for (int i = 0; i < NITER; ++i) {
    const int t1 = 2 * i + 1;
    const bool more = (i + 1 < NITER);
    // ph1: consume buf0 {B full + A q0}; stage buf1.A-lo <- tile t1
    LDB(0); LDA(0, 0); STAGE_A(t1, 0);
    BAR; LGKM0; MMA(0); BAR;
    // ph2
    LDA(0, 1); STAGE_A(t1, 1);
    BAR; LGKM0; MMA(1); BAR;
    // ph3
    LDA(0, 2); if (more) STAGE_B(t1 + 1, 0);
    BAR; LGKM0; MMA(2); BAR;
    // ph4: vmcnt(4) drains A(t1)+B(t1), leaves B(t1+1) in flight
    LDA(0, 3); if (more) STAGE_B(t1 + 1, 1);
    BAR; LGKM0; MMA(3);
    if (more) { VMCNT4; } else { VMCNT0; }
    BAR;
    // ph5: consume buf1 {B full + A q0}; stage buf0.A-lo <- tile t1+1
    LDB(1); LDA(1, 0); if (more) STAGE_A(t1 + 1, 0);
    BAR; LGKM0; MMA(0); BAR;
    // ph6
    LDA(1, 1); if (more) STAGE_A(t1 + 1, 1);
    BAR; LGKM0; MMA(1); BAR;
    // ph7
    LDA(1, 2); if (more) STAGE_B(t1 + 2, 0);
    BAR; LGKM0; MMA(2); BAR;
    // ph8: vmcnt(4) drains tile t1+1 fully, leaves B(t1+2)
    LDA(1, 3); if (more) STAGE_B(t1 + 2, 1);
    BAR; LGKM0; MMA(3); VMCNT4; BAR;
  }

  // ---- Epilogue: acc -> swizzled LDS C-tile (f16, bias fused) -> coalesced global stores
  // Swapped layout: m = bm0 + wr*128 + mi*16 + rl ; n = bn0 + wc*64 + ni*16 + 4*kg + reg
  {
    const int mloc0 = wr * 128 + rl;
    const int nq0   = wc * 64 + 4 * kg;
#pragma unroll
    for (int ni = 0; ni < 4; ++ni) {
      const int nloc = nq0 + ni * 16;
      const float4 b4 = *(const float4*)&bias_all[bn0 + nloc];
#pragma unroll
      for (int mi = 0; mi < 8; ++mi) {
        const int m = mloc0 + mi * 16;
        f16x4 h;
        h[0] = (f16)(acc[mi][ni][0] + b4.x);
        h[1] = (f16)(acc[mi][ni][1] + b4.y);
        h[2] = (f16)(acc[mi][ni][2] + b4.z);
        h[3] = (f16)(acc[mi][ni][3] + b4.w);
        *(f16x4*)&lds[m * 256 + (nloc ^ ((m & 7) << 3))] = h;
      }
    }
    LGKM0; BAR;
    const int rrow = t >> 5;       // 0..15
    const int rchk = t & 31;       // 0..31, 8 f16 each
#pragma unroll
    for (int p = 0; p < 16; ++p) {
      const int row = p * 16 + rrow;
      f16x8 vdat = *(const f16x8*)&lds[row * 256 + ((rchk * 8) ^ ((row & 7) << 3))];
      *(f16x8*)&C[(size_t)(bm0 + row) * NCOLS + bn0 + rchk * 8] = vdat;
    }
  }
}

// ---------------- Kernel 3: gather + 4-way per-feature softmax + weighted sum ----------------
// XCD-chunked block swizzle: 3136 blocks = 8 * 392; each XCD gets 392 consecutive blocks.
__global__ __launch_bounds__(256) void attend(
    const f16* __restrict__ qkv,
    const int* __restrict__ img_ids, const float* __restrict__ eps,
    const float* __restrict__ avgs, const float* __restrict__ stds,
    float* __restrict__ out) {
  const int lane = threadIdx.x & 63;
  const int wid  = threadIdx.x >> 6;
  const int logical = (blockIdx.x & 7) * 392 + (blockIdx.x >> 3);
  const int gw = logical * 4 + wid;          // (b*196 + s)
  const int b = gw / NP;
  const int s = gw - b * NP;

  const int img = img_ids[b];
  const float ex = eps[(b * 2 + 0) * NP + s];
  const float ey = eps[(b * 2 + 1) * NP + s];
  const float mux = avgs[(img * 2 + 0) * NP + s];
  const float muy = avgs[(img * 2 + 1) * NP + s];
  const float sdx = stds[(img * 2 + 0) * NP + s];
  const float sdy = stds[(img * 2 + 1) * NP + s];

  const float kx = fmaf(sdx, ex, mux);
  const float ky = fmaf(sdy, ey, muy);
  const float kx1 = ceilf(kx), kx2 = floorf(kx);
  const float ky1 = ceilf(ky), ky2 = floorf(ky);

  int idx[4];
  idx[0] = (int)fminf(fmaxf(GRIDF * ky1 + kx1, 0.0f), 195.0f);
  idx[1] = (int)fminf(fmaxf(GRIDF * ky1 + kx2, 0.0f), 195.0f);
  idx[2] = (int)fminf(fmaxf(GRIDF * ky2 + kx1, 0.0f), 195.0f);
  idx[3] = (int)fminf(fmaxf(GRIDF * ky2 + kx2, 0.0f), 195.0f);

  const f16* qrow = qkv + (size_t)gw * NCOLS;
  const f16* base = qkv + (size_t)(b * NP) * NCOLS;
  const f16* k0p = base + (size_t)idx[0] * NCOLS + DIM;
  const f16* k1p = base + (size_t)idx[1] * NCOLS + DIM;
  const f16* k2p = base + (size_t)idx[2] * NCOLS + DIM;
  const f16* k3p = base + (size_t)idx[3] * NCOLS + DIM;
  const f16* v0p = k0p + DIM;
  const f16* v1p = k1p + DIM;
  const f16* v2p = k2p + DIM;
  const f16* v3p = k3p + DIM;
  float* orow = out + (size_t)gw * DIM;

#pragma unroll
  for (int seg = 0; seg < 3; ++seg) {
    const int e0 = seg * 256 + lane * 4;
    f16x4 qv  = *(const f16x4*)(qrow + e0);
    f16x4 kv0 = *(const f16x4*)(k0p + e0);
    f16x4 kv1 = *(const f16x4*)(k1p + e0);
    f16x4 kv2 = *(const f16x4*)(k2p + e0);
    f16x4 kv3 = *(const f16x4*)(k3p + e0);
    f16x4 vv0 = *(const f16x4*)(v0p + e0);
    f16x4 vv1 = *(const f16x4*)(v1p + e0);
    f16x4 vv2 = *(const f16x4*)(v2p + e0);
    f16x4 vv3 = *(const f16x4*)(v3p + e0);
    float4 o;
    float* op = &o.x;
#pragma unroll
    for (int c = 0; c < 4; ++c) {
      const float q = (float)qv[c];
      const float s0 = q * (float)kv0[c];
      const float s1 = q * (float)kv1[c];
      const float s2 = q * (float)kv2[c];
      const float s3 = q * (float)kv3[c];
      const float mx = fmaxf(fmaxf(s0, s1), fmaxf(s2, s3));
      const float w0 = __expf(s0 - mx);
      const float w1 = __expf(s1 - mx);
      const float w2 = __expf(s2 - mx);
      const float w3 = __expf(s3 - mx);
      const float den = w0 + w1 + w2 + w3;
      const float num = w0 * (float)vv0[c] + w1 * (float)vv1[c] +
                        w2 * (float)vv2[c] + w3 * (float)vv3[c];
      op[c] = num / den;
    }
    *(float4*)(orow + e0) = o;
  }
}

// ---------------- Launch ----------------
extern "C" void kernel_launch(void* const* d_in, const int* in_sizes, int n_in,
                              void* d_out, int out_size, void* d_ws, size_t ws_size,
                              hipStream_t stream) {
  const float* x       = (const float*)d_in[0];
  const int*   img_ids = (const int*)d_in[2];
  const float* eps     = (const float*)d_in[3];
  const float* Wq      = (const float*)d_in[4];
  const float* bq      = (const float*)d_in[5];
  const float* Wk      = (const float*)d_in[6];
  const float* bk      = (const float*)d_in[7];
  const float* Wv      = (const float*)d_in[8];
  const float* bv      = (const float*)d_in[9];
  const float* avgs    = (const float*)d_in[10];
  const float* stds    = (const float*)d_in[11];
  float* out = (float*)d_out;

  char* ws = (char*)d_ws;
  const size_t XH_BYTES = (size_t)MROWS * DIM * 2;   // 19,267,584
  const size_t WH_BYTES = (size_t)NCOLS * DIM * 2;   //  3,538,944
  const size_t BI_BYTES = (size_t)NCOLS * 4;         //      9,216
  f16*   x_h      = (f16*)ws;
  f16*   W_h      = (f16*)(ws + XH_BYTES);
  float* bias_all = (float*)(ws + XH_BYTES + WH_BYTES);
  f16*   qkv      = (f16*)(ws + XH_BYTES + WH_BYTES + BI_BYTES);

  {
    int grid = (NCVTA + 255) / 256;
    convert_inputs<<<grid, 256, 0, stream>>>(x, Wq, Wk, Wv, bq, bk, bv, x_h, W_h, bias_all);
  }
  {
    gemm_qkv<<<441, 512, 0, stream>>>(x_h, W_h, bias_all, qkv);
  }
  {
    int grid = MROWS / 4;
    attend<<<grid, 256, 0, stream>>>(qkv, img_ids, eps, avgs, stds, out);
  }
}